// Round 1
// baseline (421.567 us; speedup 1.0000x reference)
//
#include <hip/hip_runtime.h>
#include <stdint.h>

// ---------------------------------------------------------------------------
// Single-head attention: out = proj(softmax(QK^T/sqrt(D)) V)
// B=4, S=2048, D=1024, fp32 in/out. All heavy math in bf16 MFMA w/ fp32 acc.
//
// Pipeline (all launched on `stream`):
//  1. q  = query @ Wq^T + bq      (f32 in -> bf16 out)       [8192,1024]
//  2. k  = key   @ Wk^T + bk      (f32 in -> bf16 out)       [8192,1024]
//  3. vT = Wv @ value^T + bv      (f32 in -> bf16 out)       [1024,8192]
//  4. S  = q @ k^T * 1/32         (bf16 -> bf16, batched z=4)[4,2048,2048]
//  5. softmax rows of S in place  (fp32 math)
//  6. o  = P @ vT^T               (bf16 -> bf16, batched)    [8192,1024]
//  7. out= o @ Wo^T + bo          (bf16/f32 -> f32)          [8192,1024]
//
// ws usage: q(16.8M) k(16.8M) vT(16.8M) P(33.6M) o(16.8M) = 100,663,296 B
// ---------------------------------------------------------------------------

typedef __bf16  bf16x8 __attribute__((ext_vector_type(8)));
typedef float   f32x4  __attribute__((ext_vector_type(4)));
typedef unsigned int u32x4 __attribute__((ext_vector_type(4)));

__device__ __forceinline__ unsigned short bf16_rne(float f) {
  unsigned int u = __builtin_bit_cast(unsigned int, f);
  u += 0x7FFFu + ((u >> 16) & 1u);   // round-to-nearest-even (no NaN inputs)
  return (unsigned short)(u >> 16);
}
__device__ __forceinline__ unsigned int pack2(float a, float b) {
  return (unsigned int)bf16_rne(a) | ((unsigned int)bf16_rne(b) << 16);
}

// ---------------------------------------------------------------------------
// C[m][n] = scale * sum_k A[m][k] * B[n][k]  (+ bias)   -- B^T GEMM
// Tile 128x128, BK=64, 256 threads = 4 waves in 2x2, each wave 64x64 (4x4
// fragments of 16x16x32 bf16 MFMA). LDS rows padded to 72 elems (144 B) so
// fragment ds_read_b128 aliases only 2-way (free, m136).
// M = gridDim.y*128, N = gridDim.x*128, K % 64 == 0. All dims multiples of 128.
// TA_F32/TB_F32: operand is fp32 in global, converted to bf16 during staging.
// ---------------------------------------------------------------------------
template<int TA_F32, int TB_F32, int OUT_F32>
__global__ __launch_bounds__(256) void gemm_bt(
    const void* __restrict__ Ap, const void* __restrict__ Bp,
    void* __restrict__ Cp,
    int K, int lda, int ldb, int ldc,
    long sAz, long sBz, long sCz,
    float scale, const float* __restrict__ bias, int bias_mode)
{
  __shared__ unsigned short As[128][72];
  __shared__ unsigned short Bs[128][72];

  const int tid  = threadIdx.x;
  const int bm   = blockIdx.y * 128;
  const int bn   = blockIdx.x * 128;
  const long z   = blockIdx.z;

  const int lane = tid & 63;
  const int wid  = tid >> 6;
  const int wr   = (wid >> 1) * 64;   // wave row offset in tile
  const int wc   = (wid & 1)  * 64;   // wave col offset in tile
  const int al   = lane & 15;
  const int ah   = lane >> 4;

  f32x4 acc[4][4] = {};

  const int nkt = K >> 6;
  for (int kt = 0; kt < nkt; ++kt) {
    const int k0 = kt << 6;
    __syncthreads();                  // protect LDS from previous compute
    #pragma unroll
    for (int it = 0; it < 4; ++it) {
      const int chunk = tid + it * 256;       // 1024 chunks of 8 elems/tile
      const int r = chunk >> 3;               // 0..127
      const int c = (chunk & 7) << 3;         // 0..56
      u32x4 wa, wb;
      if (TA_F32) {
        const float* src = (const float*)Ap + z * sAz + (long)(bm + r) * lda + (k0 + c);
        f32x4 f0 = *(const f32x4*)(src);
        f32x4 f1 = *(const f32x4*)(src + 4);
        wa[0] = pack2(f0[0], f0[1]); wa[1] = pack2(f0[2], f0[3]);
        wa[2] = pack2(f1[0], f1[1]); wa[3] = pack2(f1[2], f1[3]);
      } else {
        const unsigned short* src = (const unsigned short*)Ap + z * sAz + (long)(bm + r) * lda + (k0 + c);
        wa = *(const u32x4*)src;
      }
      if (TB_F32) {
        const float* src = (const float*)Bp + z * sBz + (long)(bn + r) * ldb + (k0 + c);
        f32x4 f0 = *(const f32x4*)(src);
        f32x4 f1 = *(const f32x4*)(src + 4);
        wb[0] = pack2(f0[0], f0[1]); wb[1] = pack2(f0[2], f0[3]);
        wb[2] = pack2(f1[0], f1[1]); wb[3] = pack2(f1[2], f1[3]);
      } else {
        const unsigned short* src = (const unsigned short*)Bp + z * sBz + (long)(bn + r) * ldb + (k0 + c);
        wb = *(const u32x4*)src;
      }
      *(u32x4*)&As[r][c] = wa;
      *(u32x4*)&Bs[r][c] = wb;
    }
    __syncthreads();

    #pragma unroll
    for (int kk = 0; kk < 2; ++kk) {
      bf16x8 af[4], bfr[4];
      #pragma unroll
      for (int m = 0; m < 4; ++m)
        af[m] = *(const bf16x8*)&As[wr + m * 16 + al][kk * 32 + ah * 8];
      #pragma unroll
      for (int n = 0; n < 4; ++n)
        bfr[n] = *(const bf16x8*)&Bs[wc + n * 16 + al][kk * 32 + ah * 8];
      #pragma unroll
      for (int m = 0; m < 4; ++m)
        #pragma unroll
        for (int n = 0; n < 4; ++n)
          acc[m][n] = __builtin_amdgcn_mfma_f32_16x16x32_bf16(af[m], bfr[n], acc[m][n], 0, 0, 0);
    }
  }

  // Epilogue. C/D layout (verified m89/m91): col = lane&15, row = (lane>>4)*4 + j
  #pragma unroll
  for (int m = 0; m < 4; ++m) {
    #pragma unroll
    for (int n = 0; n < 4; ++n) {
      #pragma unroll
      for (int j = 0; j < 4; ++j) {
        const int grow = bm + wr + m * 16 + ah * 4 + j;
        const int gcol = bn + wc + n * 16 + al;
        float v = acc[m][n][j] * scale;
        if (bias_mode == 1)      v += bias[gcol];
        else if (bias_mode == 2) v += bias[grow];
        const long idx = z * sCz + (long)grow * ldc + gcol;
        if (OUT_F32) ((float*)Cp)[idx] = v;
        else         ((unsigned short*)Cp)[idx] = bf16_rne(v);
      }
    }
  }
}

// ---------------------------------------------------------------------------
// In-place row softmax over 2048 bf16 cols. One block (256 thr) per row; each
// thread owns 8 contiguous elems, so read-then-write in-place is race-free.
// ---------------------------------------------------------------------------
__global__ __launch_bounds__(256) void softmax_inplace(unsigned short* __restrict__ P) {
  const long row = blockIdx.x;
  unsigned short* pr = P + row * 2048;
  const int tid = threadIdx.x;

  u32x4 raw = *(const u32x4*)&pr[tid * 8];
  float s[8];
  #pragma unroll
  for (int i = 0; i < 4; ++i) {
    unsigned int u = raw[i];
    s[2 * i]     = __builtin_bit_cast(float, u << 16);
    s[2 * i + 1] = __builtin_bit_cast(float, u & 0xFFFF0000u);
  }
  float m = s[0];
  #pragma unroll
  for (int i = 1; i < 8; ++i) m = fmaxf(m, s[i]);
  #pragma unroll
  for (int off = 32; off >= 1; off >>= 1) m = fmaxf(m, __shfl_xor(m, off));

  __shared__ float redm[4], reds[4];
  const int wid = tid >> 6, lane = tid & 63;
  if (lane == 0) redm[wid] = m;
  __syncthreads();
  m = fmaxf(fmaxf(redm[0], redm[1]), fmaxf(redm[2], redm[3]));

  float e[8], sum = 0.f;
  #pragma unroll
  for (int i = 0; i < 8; ++i) { e[i] = __expf(s[i] - m); sum += e[i]; }
  #pragma unroll
  for (int off = 32; off >= 1; off >>= 1) sum += __shfl_xor(sum, off);
  if (lane == 0) reds[wid] = sum;
  __syncthreads();
  sum = reds[0] + reds[1] + reds[2] + reds[3];
  const float inv = 1.0f / sum;

  u32x4 outw;
  #pragma unroll
  for (int i = 0; i < 4; ++i) outw[i] = pack2(e[2 * i] * inv, e[2 * i + 1] * inv);
  *(u32x4*)&pr[tid * 8] = outw;
}

// ---------------------------------------------------------------------------
extern "C" void kernel_launch(void* const* d_in, const int* in_sizes, int n_in,
                              void* d_out, int out_size, void* d_ws, size_t ws_size,
                              hipStream_t stream) {
  const float* query = (const float*)d_in[0];
  const float* key_  = (const float*)d_in[1];
  const float* value = (const float*)d_in[2];
  const float* Wq    = (const float*)d_in[3];
  const float* bq    = (const float*)d_in[4];
  const float* Wk    = (const float*)d_in[5];
  const float* bk    = (const float*)d_in[6];
  const float* Wv    = (const float*)d_in[7];
  const float* bv    = (const float*)d_in[8];
  const float* Wo    = (const float*)d_in[9];
  const float* bo    = (const float*)d_in[10];

  // workspace carve (all 16B-aligned; total 100,663,296 bytes)
  unsigned short* q  = (unsigned short*)d_ws;            // [8192][1024]
  unsigned short* k  = q  + 8388608;                     // [8192][1024]
  unsigned short* vT = k  + 8388608;                     // [1024][8192]
  unsigned short* P  = vT + 8388608;                     // [4][2048][2048]
  unsigned short* o  = P  + 16777216;                    // [8192][1024]

  const dim3 blk(256);

  // 1,2: q/k projections (f32 inputs -> bf16 out). M=8192, N=1024, K=1024.
  gemm_bt<1,1,0><<<dim3(8, 64, 1), blk, 0, stream>>>(query, Wq, q,
      1024, 1024, 1024, 1024, 0L, 0L, 0L, 1.0f, bq, 1);
  gemm_bt<1,1,0><<<dim3(8, 64, 1), blk, 0, stream>>>(key_, Wk, k,
      1024, 1024, 1024, 1024, 0L, 0L, 0L, 1.0f, bk, 1);

  // 3: vT = Wv @ value^T + bv. M=1024, N=8192, K=1024, bias per-row.
  gemm_bt<1,1,0><<<dim3(64, 8, 1), blk, 0, stream>>>(Wv, value, vT,
      1024, 1024, 1024, 8192, 0L, 0L, 0L, 1.0f, bv, 2);

  // 4: scores = q @ k^T / 32, batched over z=4. M=N=2048, K=1024.
  gemm_bt<0,0,0><<<dim3(16, 16, 4), blk, 0, stream>>>(q, k, P,
      1024, 1024, 1024, 2048, 2097152L, 2097152L, 4194304L, 0.03125f, nullptr, 0);

  // 5: softmax rows in place (8192 rows x 2048)
  softmax_inplace<<<dim3(8192), blk, 0, stream>>>(P);

  // 6: o = P @ vT^T, batched. M=2048, N=1024, K=2048.
  gemm_bt<0,0,0><<<dim3(8, 16, 4), blk, 0, stream>>>(P, vT, o,
      2048, 2048, 8192, 1024, 4194304L, 2048L, 2097152L, 1.0f, nullptr, 0);

  // 7: out = o @ Wo^T + bo (fp32 out). M=8192, N=1024, K=1024.
  gemm_bt<0,1,1><<<dim3(8, 64, 1), blk, 0, stream>>>(o, Wo, d_out,
      1024, 1024, 1024, 1024, 0L, 0L, 0L, 1.0f, bo, 1);
}

// Round 2
// 308.804 us; speedup vs baseline: 1.3652x; 1.3652x over previous
//
#include <hip/hip_runtime.h>
#include <stdint.h>

// ---------------------------------------------------------------------------
// Single-head attention: out = proj(softmax(QK^T/sqrt(D)) V)
// B=4, S=2048, D=1024, fp32 in/out. All heavy math in bf16 MFMA w/ fp32 acc.
//
// Pipeline:
//  0. convert fp32 -> bf16: query,key -> qf,kf; weights Wq..Wo -> Wb; bias copy
//  1. [q;k] = [qf;kf] @ [Wq;Wk]^T + [bq;bk]   (z-batched, bf16)
//  2. convert value -> vf (overlays dead qf)
//  3. vT = Wv @ vf^T + bv                      [1024,8192] bf16
//  4. P  = q @ k^T / 32  (z=4)                 [4,2048,2048] bf16 (overlays qf/kf/vf)
//  5. softmax rows of P in place
//  6. o  = P @ vT^T (z=4)                      [8192,1024] bf16 (overlays dead q)
//  7. out= o @ Wo^T + bo                       fp32 -> d_out
//
// GEMM: m97 structure — 128x128 tile, BK=64, 4 waves, linear LDS staged via
// global_load_lds dwordx4 (16B), 2 barriers per K-step, 16x16x32 bf16 MFMA.
//
// ws layout (ushort units):
//   off 0        : qf (8.4M) -> vf -> P[0..] (16.8M total with next)
//   off 8388608  : kf        -> P[8.4M..]
//   off 16777216 : q         -> o
//   off 25165824 : k
//   off 33554432 : vT
//   off 41943040 : Wb (4x1M bf16)
//   off 46137344 : biases (2048 fp32 = 4096 ushort)  => total 92.3 MB
// ---------------------------------------------------------------------------

typedef __bf16  bf16x8 __attribute__((ext_vector_type(8)));
typedef float   f32x4  __attribute__((ext_vector_type(4)));
typedef unsigned int u32x4 __attribute__((ext_vector_type(4)));

__device__ __forceinline__ unsigned short bf16_rne(float f) {
  unsigned int u = __builtin_bit_cast(unsigned int, f);
  u += 0x7FFFu + ((u >> 16) & 1u);   // round-to-nearest-even (no NaN inputs)
  return (unsigned short)(u >> 16);
}
__device__ __forceinline__ unsigned int pack2(float a, float b) {
  return (unsigned int)bf16_rne(a) | ((unsigned int)bf16_rne(b) << 16);
}

__device__ __forceinline__ void async16(const unsigned short* g, unsigned short* l) {
  // 16B per lane: global per-lane src -> LDS wave-uniform base + lane*16
  __builtin_amdgcn_global_load_lds(
      (const __attribute__((address_space(1))) unsigned int*)g,
      (__attribute__((address_space(3))) unsigned int*)l,
      16, 0, 0);
}

// ---------------------------------------------------------------------------
// C[z][m][n] = scale * sum_k A[z][m][k] * B[z][n][k]  (+ bias)   -- B^T GEMM
// ---------------------------------------------------------------------------
template<int OUT_F32>
__global__ __launch_bounds__(256) void gemm_bt(
    const unsigned short* __restrict__ A, const unsigned short* __restrict__ B,
    void* __restrict__ Cp,
    int K, int lda, int ldb, int ldc,
    long sAz, long sBz, long sCz, long sBiasZ,
    float scale, const float* __restrict__ bias, int bias_mode)
{
  __shared__ unsigned short As[128 * 64];
  __shared__ unsigned short Bs[128 * 64];

  const int tid  = threadIdx.x;
  const int lane = tid & 63;
  const int wid  = tid >> 6;
  const int bm   = blockIdx.y * 128;
  const int bn   = blockIdx.x * 128;
  const long z   = blockIdx.z;

  const unsigned short* Az = A + z * sAz;
  const unsigned short* Bz = B + z * sBz;

  const int wr = (wid >> 1) * 64;     // wave row offset in tile
  const int wc = (wid & 1)  * 64;     // wave col offset in tile
  const int al = lane & 15;
  const int ah = lane >> 4;

  // staging geometry: per wave 4 chunks of A + 4 of B per K-step.
  // chunk q = wid*4+i covers rows q*8 + (lane>>3), col (lane&7)*8 of the
  // [128][64] tile; LDS linear dest base = q*512 ushorts (+ lane*8 by HW).
  const int srow = lane >> 3;          // 0..7
  const int scol = (lane & 7) << 3;    // 0..56

  f32x4 acc[4][4] = {};

  const int nkt = K >> 6;
  for (int kt = 0; kt < nkt; ++kt) {
    const int k0 = kt << 6;
    #pragma unroll
    for (int i = 0; i < 4; ++i) {
      const int q = wid * 4 + i;
      const int r = q * 8 + srow;
      async16(Az + (long)(bm + r) * lda + (k0 + scol), &As[q * 512]);
      async16(Bz + (long)(bn + r) * ldb + (k0 + scol), &Bs[q * 512]);
    }
    __syncthreads();                   // drains vmcnt(0): tiles ready

    #pragma unroll
    for (int kk = 0; kk < 2; ++kk) {
      bf16x8 af[4], bfr[4];
      #pragma unroll
      for (int m = 0; m < 4; ++m)
        af[m] = *(const bf16x8*)&As[(wr + m * 16 + al) * 64 + kk * 32 + ah * 8];
      #pragma unroll
      for (int n = 0; n < 4; ++n)
        bfr[n] = *(const bf16x8*)&Bs[(wc + n * 16 + al) * 64 + kk * 32 + ah * 8];
      #pragma unroll
      for (int m = 0; m < 4; ++m)
        #pragma unroll
        for (int n = 0; n < 4; ++n)
          acc[m][n] = __builtin_amdgcn_mfma_f32_16x16x32_bf16(af[m], bfr[n], acc[m][n], 0, 0, 0);
    }
    __syncthreads();                   // all waves done reading before overwrite
  }

  // Epilogue. C/D layout (m89/m91): col = lane&15, row = (lane>>4)*4 + j
  #pragma unroll
  for (int m = 0; m < 4; ++m) {
    #pragma unroll
    for (int n = 0; n < 4; ++n) {
      #pragma unroll
      for (int j = 0; j < 4; ++j) {
        const int grow = bm + wr + m * 16 + ah * 4 + j;
        const int gcol = bn + wc + n * 16 + al;
        float v = acc[m][n][j] * scale;
        if (bias_mode == 1)      v += bias[z * sBiasZ + gcol];
        else if (bias_mode == 2) v += bias[z * sBiasZ + grow];
        const long idx = z * sCz + (long)grow * ldc + gcol;
        if (OUT_F32) ((float*)Cp)[idx] = v;
        else         ((unsigned short*)Cp)[idx] = bf16_rne(v);
      }
    }
  }
}

// ---------------------------------------------------------------------------
// fp32 -> bf16 convert, 8 elems/thread. n must be a multiple of 8 (it is).
// ---------------------------------------------------------------------------
__global__ __launch_bounds__(256) void cvt_f32_bf16(
    const float* __restrict__ in, unsigned short* __restrict__ out, int n8)
{
  const int i = blockIdx.x * 256 + threadIdx.x;
  if (i >= n8) return;
  f32x4 a = *(const f32x4*)(in + (long)i * 8);
  f32x4 b = *(const f32x4*)(in + (long)i * 8 + 4);
  u32x4 w;
  w[0] = pack2(a[0], a[1]); w[1] = pack2(a[2], a[3]);
  w[2] = pack2(b[0], b[1]); w[3] = pack2(b[2], b[3]);
  *(u32x4*)(out + (long)i * 8) = w;
}

__global__ __launch_bounds__(256) void copy_bias2(
    const float* __restrict__ b0, const float* __restrict__ b1, float* __restrict__ dst)
{
  const int t = blockIdx.x * 256 + threadIdx.x;   // grid 8 -> 2048 threads
  if (t < 1024)       dst[t] = b0[t];
  else if (t < 2048)  dst[t] = b1[t - 1024];
}

// ---------------------------------------------------------------------------
// In-place row softmax over 2048 bf16 cols. One block per row, 8 elems/thread.
// ---------------------------------------------------------------------------
__global__ __launch_bounds__(256) void softmax_inplace(unsigned short* __restrict__ P) {
  const long row = blockIdx.x;
  unsigned short* pr = P + row * 2048;
  const int tid = threadIdx.x;

  u32x4 raw = *(const u32x4*)&pr[tid * 8];
  float s[8];
  #pragma unroll
  for (int i = 0; i < 4; ++i) {
    unsigned int u = raw[i];
    s[2 * i]     = __builtin_bit_cast(float, u << 16);
    s[2 * i + 1] = __builtin_bit_cast(float, u & 0xFFFF0000u);
  }
  float m = s[0];
  #pragma unroll
  for (int i = 1; i < 8; ++i) m = fmaxf(m, s[i]);
  #pragma unroll
  for (int off = 32; off >= 1; off >>= 1) m = fmaxf(m, __shfl_xor(m, off));

  __shared__ float redm[4], reds[4];
  const int wid = tid >> 6, lane = tid & 63;
  if (lane == 0) redm[wid] = m;
  __syncthreads();
  m = fmaxf(fmaxf(redm[0], redm[1]), fmaxf(redm[2], redm[3]));

  float e[8], sum = 0.f;
  #pragma unroll
  for (int i = 0; i < 8; ++i) { e[i] = __expf(s[i] - m); sum += e[i]; }
  #pragma unroll
  for (int off = 32; off >= 1; off >>= 1) sum += __shfl_xor(sum, off);
  if (lane == 0) reds[wid] = sum;
  __syncthreads();
  sum = reds[0] + reds[1] + reds[2] + reds[3];
  const float inv = 1.0f / sum;

  u32x4 outw;
  #pragma unroll
  for (int i = 0; i < 4; ++i) outw[i] = pack2(e[2 * i] * inv, e[2 * i + 1] * inv);
  *(u32x4*)&pr[tid * 8] = outw;
}

// ---------------------------------------------------------------------------
extern "C" void kernel_launch(void* const* d_in, const int* in_sizes, int n_in,
                              void* d_out, int out_size, void* d_ws, size_t ws_size,
                              hipStream_t stream) {
  const float* query = (const float*)d_in[0];
  const float* key_  = (const float*)d_in[1];
  const float* value = (const float*)d_in[2];
  const float* Wq    = (const float*)d_in[3];
  const float* bq    = (const float*)d_in[4];
  const float* Wk    = (const float*)d_in[5];
  const float* bk    = (const float*)d_in[6];
  const float* Wv    = (const float*)d_in[7];
  const float* bv    = (const float*)d_in[8];
  const float* Wo    = (const float*)d_in[9];
  const float* bo    = (const float*)d_in[10];

  unsigned short* ws = (unsigned short*)d_ws;
  unsigned short* qf = ws;                        // [8192][1024] -> vf -> P lower
  unsigned short* kf = ws + 8388608;              // [8192][1024] -> P upper
  unsigned short* vf = ws;                        // overlays dead qf
  unsigned short* P  = ws;                        // [4][2048][2048] overlays qf+kf
  unsigned short* q  = ws + 16777216;             // [2][2048][1024] -> later o
  unsigned short* k  = ws + 25165824;             // [4? no: batch rows of k]
  unsigned short* vT = ws + 33554432;             // [1024][8192]
  unsigned short* Wb = ws + 41943040;             // 4 x [1024][1024] bf16
  float*          bqk= (float*)(ws + 46137344);   // [2][1024] fp32
  unsigned short* o  = q;                         // overlays dead q

  const dim3 blk(256);

  // 0: conversions
  cvt_f32_bf16<<<dim3(512, 1, 1), blk, 0, stream>>>(Wq, Wb,            131072);
  cvt_f32_bf16<<<dim3(512, 1, 1), blk, 0, stream>>>(Wk, Wb + 1048576,  131072);
  cvt_f32_bf16<<<dim3(512, 1, 1), blk, 0, stream>>>(Wv, Wb + 2097152,  131072);
  cvt_f32_bf16<<<dim3(512, 1, 1), blk, 0, stream>>>(Wo, Wb + 3145728,  131072);
  copy_bias2<<<dim3(8), blk, 0, stream>>>(bq, bk, bqk);
  cvt_f32_bf16<<<dim3(4096, 1, 1), blk, 0, stream>>>(query, qf, 1048576);
  cvt_f32_bf16<<<dim3(4096, 1, 1), blk, 0, stream>>>(key_,  kf, 1048576);

  // 1: [q;k] projections, z-batched. M=8192,N=1024,K=1024 per z.
  gemm_bt<0><<<dim3(8, 64, 2), blk, 0, stream>>>(qf, Wb, q,
      1024, 1024, 1024, 1024, 8388608L, 1048576L, 8388608L, 1024L, 1.0f, bqk, 1);

  // 2: convert value (into region freed by qf)
  cvt_f32_bf16<<<dim3(4096, 1, 1), blk, 0, stream>>>(value, vf, 1048576);

  // 3: vT = Wv @ vf^T + bv. M=1024, N=8192, K=1024, bias per-row.
  gemm_bt<0><<<dim3(64, 8, 1), blk, 0, stream>>>(Wb + 2097152, vf, vT,
      1024, 1024, 1024, 8192, 0L, 0L, 0L, 0L, 1.0f, bv, 2);

  // 4: P = q @ k^T / 32, z=4. M=N=2048, K=1024.
  gemm_bt<0><<<dim3(16, 16, 4), blk, 0, stream>>>(q, q + 8388608, P,
      1024, 1024, 1024, 2048, 2097152L, 2097152L, 4194304L, 0L, 0.03125f, nullptr, 0);

  // 5: softmax rows in place (8192 rows x 2048)
  softmax_inplace<<<dim3(8192), blk, 0, stream>>>(P);

  // 6: o = P @ vT^T, z=4. M=2048, N=1024, K=2048.
  gemm_bt<0><<<dim3(8, 16, 4), blk, 0, stream>>>(P, vT, o,
      2048, 2048, 8192, 1024, 4194304L, 2048L, 2097152L, 0L, 1.0f, nullptr, 0);

  // 7: out = o @ Wo^T + bo (fp32 out). M=8192, N=1024, K=1024.
  gemm_bt<1><<<dim3(8, 64, 1), blk, 0, stream>>>(o, Wb + 3145728, d_out,
      1024, 1024, 1024, 1024, 0L, 0L, 0L, 0L, 1.0f, bo, 1);
}

// Round 3
// 282.229 us; speedup vs baseline: 1.4937x; 1.0942x over previous
//
#include <hip/hip_runtime.h>
#include <stdint.h>

// ---------------------------------------------------------------------------
// Single-head attention, B=4, S=2048, D=1024, fp32 in/out. bf16 MFMA pipeline.
//
//  0. cvt fp32->bf16: query,key -> qf,kf; weights -> Wb; bias copy
//  1. [q;k] = [qf;kf] @ [Wq;Wk]^T + b    (z=2 batched)
//  2. cvt value -> vf (overlays dead qf)
//  3. vT = Wv @ vf^T + bv                 [1024,8192]
//  4. P  = q @ k^T / 32 (z=4)             [4,2048,2048] (overlays qf/kf/vf)
//  5. softmax rows of P in place
//  6. o  = P @ vT^T (z=4)                 (overlays dead q)
//  7. out= o @ Wo^T + bo -> d_out (fp32)
//
// GEMM engine (T2+T3+T4+T5 stack):
//   BM=256 BN=128 BK=64, 512 thr = 8 waves (4M x 2N), per-wave 64x64.
//   3-buffer LDS ring (3 x 48KB = 144KB): compute tile t from buf[t%3] while
//   tiles t+1,t+2 are in flight -> top-of-iter s_waitcnt vmcnt(6), never 0.
//   4 phases per K-tile: {ds_read frags | 2x global_load_lds -> s_barrier ->
//   setprio(1) 8xMFMA setprio(0) -> s_barrier}. Raw barriers (no vmcnt drain).
//   T2 swizzle: 16B unit ^= (row&7); DMA dest linear, global SOURCE
//   pre-swizzled (rule #21), ds_read address swizzled -> 2-way aliasing only.
// ---------------------------------------------------------------------------

typedef __bf16  bf16x8 __attribute__((ext_vector_type(8)));
typedef float   f32x4  __attribute__((ext_vector_type(4)));
typedef unsigned int u32x4 __attribute__((ext_vector_type(4)));

__device__ __forceinline__ unsigned short bf16_rne(float f) {
  unsigned int u = __builtin_bit_cast(unsigned int, f);
  u += 0x7FFFu + ((u >> 16) & 1u);
  return (unsigned short)(u >> 16);
}
__device__ __forceinline__ unsigned int pack2(float a, float b) {
  return (unsigned int)bf16_rne(a) | ((unsigned int)bf16_rne(b) << 16);
}
__device__ __forceinline__ void async16(const unsigned short* g, unsigned short* l) {
  __builtin_amdgcn_global_load_lds(
      (const __attribute__((address_space(1))) unsigned int*)g,
      (__attribute__((address_space(3))) unsigned int*)l,
      16, 0, 0);
}

#define FENCE() asm volatile("" ::: "memory")
#define BAR()   __builtin_amdgcn_s_barrier()

// ---------------------------------------------------------------------------
// C[z][m][n] = scale * sum_k A[z][m][k] * B[z][n][k]  (+ bias)
// M % 256 == 0, N % 128 == 0, K % 64 == 0, K >= 128.
// ---------------------------------------------------------------------------
template<int OUT_F32>
__global__ __launch_bounds__(512, 2) void gemm8(
    const unsigned short* __restrict__ A, const unsigned short* __restrict__ B,
    void* __restrict__ Cp,
    int K, int lda, int ldb, int ldc,
    long sAz, long sBz, long sCz, long sBiasZ,
    float scale, const float* __restrict__ bias, int bias_mode)
{
  __shared__ unsigned short lds[3 * 24576];   // per buf: A 16384 + B 8192 ushorts

  const int tid  = threadIdx.x;
  const int lane = tid & 63;
  const int wid  = tid >> 6;                  // 0..7
  const int bm   = blockIdx.y * 256;
  const int bn   = blockIdx.x * 128;
  const long z   = blockIdx.z;

  const unsigned short* Az = A + z * sAz;
  const unsigned short* Bz = B + z * sBz;

  const int wr  = (wid >> 1) * 64;            // wave row in tile (0,64,128,192)
  const int wc  = (wid & 1)  * 64;            // wave col in tile (0,64)
  const int al  = lane & 15;
  const int ah  = lane >> 4;
  const int al7 = lane & 7;

  // staging: per K-tile, per wave: 4 A-loads (8 rows each) + 2 B-loads.
  // global source col pre-swizzled so linear DMA dest yields swizzled LDS.
  const int swz = ((lane & 7) ^ ((lane >> 3) & 7)) << 3;   // ushort offset
  const unsigned short* Apt = Az + (long)(bm + wid * 32 + (lane >> 3)) * lda + swz;
  const unsigned short* Bpt = Bz + (long)(bn + wid * 16 + (lane >> 3)) * ldb + swz;
  const long a8 = (long)lda * 8, b8 = (long)ldb * 8;

  f32x4 acc[4][4] = {};
  const int nkt = K >> 6;

#define STAGE_A01(kt, stg) { const unsigned short* a_ = Apt + ((long)(kt) << 6); \
    async16(a_,      (stg) + wid * 2048);        \
    async16(a_ + a8, (stg) + wid * 2048 + 512); }
#define STAGE_A23(kt, stg) { const unsigned short* a_ = Apt + ((long)(kt) << 6) + 2 * a8; \
    async16(a_,      (stg) + wid * 2048 + 1024); \
    async16(a_ + a8, (stg) + wid * 2048 + 1536); }
#define STAGE_B01(kt, stg) { const unsigned short* b_ = Bpt + ((long)(kt) << 6); \
    async16(b_,      (stg) + 16384 + wid * 1024); \
    async16(b_ + b8, (stg) + 16384 + wid * 1024 + 512); }

  // swizzled fragment reads: 16B unit index (kk*4+ah) ^ (row&7), row&7 == al7
#define LDA_(m) { const int r_ = (wr + (m) * 16 + al) * 64; \
    af##m##0 = *(const bf16x8*)&as[r_ + ((ah ^ al7) << 3)]; \
    af##m##1 = *(const bf16x8*)&as[r_ + (((4 | ah) ^ al7) << 3)]; }
#define LDB_(n) { const int r_ = (wc + (n) * 16 + al) * 64; \
    bf##n##0 = *(const bf16x8*)&bs[r_ + ((ah ^ al7) << 3)]; \
    bf##n##1 = *(const bf16x8*)&bs[r_ + (((4 | ah) ^ al7) << 3)]; }
#define MM(m, n) { \
    acc[m][n] = __builtin_amdgcn_mfma_f32_16x16x32_bf16(af##m##0, bf##n##0, acc[m][n], 0, 0, 0); \
    acc[m][n] = __builtin_amdgcn_mfma_f32_16x16x32_bf16(af##m##1, bf##n##1, acc[m][n], 0, 0, 0); }

  // prologue: tiles 0,1 -> bufs 0,1 (12 loads in flight)
  STAGE_A01(0, lds); STAGE_A23(0, lds); STAGE_B01(0, lds);
  STAGE_A01(1, lds + 24576); STAGE_A23(1, lds + 24576); STAGE_B01(1, lds + 24576);

  int cur = 0;
  for (int t = 0; t < nkt; ++t) {
    const int stb  = (cur >= 1) ? cur - 1 : cur + 2;   // (t+2)%3
    const bool more = (t + 2) < nkt;

    // ensure tile t resident: everything except the newest <=6 loads (tile t+1)
    if (t + 1 < nkt) asm volatile("s_waitcnt vmcnt(6)" ::: "memory");
    else             asm volatile("s_waitcnt vmcnt(0)" ::: "memory");
    BAR(); FENCE();

    const unsigned short* as  = lds + cur * 24576;
    const unsigned short* bs  = as + 16384;
    unsigned short*       stg = lds + stb * 24576;

    bf16x8 af00, af01, af10, af11, af20, af21, af30, af31;
    bf16x8 bf00, bf01, bf10, bf11, bf20, bf21, bf30, bf31;

    // phase 0
    LDA_(0); LDA_(1); LDB_(0); LDB_(1);
    FENCE(); BAR();
    __builtin_amdgcn_s_setprio(1);
    MM(0,0); MM(0,1); MM(1,0); MM(1,1);
    __builtin_amdgcn_s_setprio(0);
    BAR(); FENCE();

    // phase 1
    LDA_(2); LDA_(3);
    if (more) STAGE_A01(t + 2, stg);
    FENCE(); BAR();
    __builtin_amdgcn_s_setprio(1);
    MM(2,0); MM(2,1); MM(3,0); MM(3,1);
    __builtin_amdgcn_s_setprio(0);
    BAR(); FENCE();

    // phase 2
    LDB_(2); LDB_(3);
    if (more) STAGE_A23(t + 2, stg);
    FENCE(); BAR();
    __builtin_amdgcn_s_setprio(1);
    MM(0,2); MM(0,3); MM(1,2); MM(1,3);
    __builtin_amdgcn_s_setprio(0);
    BAR(); FENCE();

    // phase 3
    if (more) STAGE_B01(t + 2, stg);
    FENCE(); BAR();
    __builtin_amdgcn_s_setprio(1);
    MM(2,2); MM(2,3); MM(3,2); MM(3,3);
    __builtin_amdgcn_s_setprio(0);
    BAR(); FENCE();

    cur = (cur == 2) ? 0 : cur + 1;
  }

  // Epilogue. C/D layout (m89/m91): col = lane&15, row = (lane>>4)*4 + j
  #pragma unroll
  for (int m = 0; m < 4; ++m) {
    #pragma unroll
    for (int n = 0; n < 4; ++n) {
      #pragma unroll
      for (int j = 0; j < 4; ++j) {
        const int grow = bm + wr + m * 16 + ah * 4 + j;
        const int gcol = bn + wc + n * 16 + al;
        float v = acc[m][n][j] * scale;
        if (bias_mode == 1)      v += bias[z * sBiasZ + gcol];
        else if (bias_mode == 2) v += bias[z * sBiasZ + grow];
        const long idx = z * sCz + (long)grow * ldc + gcol;
        if (OUT_F32) ((float*)Cp)[idx] = v;
        else         ((unsigned short*)Cp)[idx] = bf16_rne(v);
      }
    }
  }
}

// ---------------------------------------------------------------------------
__global__ __launch_bounds__(256) void cvt_f32_bf16(
    const float* __restrict__ in, unsigned short* __restrict__ out, int n8)
{
  const int i = blockIdx.x * 256 + threadIdx.x;
  if (i >= n8) return;
  f32x4 a = *(const f32x4*)(in + (long)i * 8);
  f32x4 b = *(const f32x4*)(in + (long)i * 8 + 4);
  u32x4 w;
  w[0] = pack2(a[0], a[1]); w[1] = pack2(a[2], a[3]);
  w[2] = pack2(b[0], b[1]); w[3] = pack2(b[2], b[3]);
  *(u32x4*)(out + (long)i * 8) = w;
}

__global__ __launch_bounds__(256) void copy_bias2(
    const float* __restrict__ b0, const float* __restrict__ b1, float* __restrict__ dst)
{
  const int t = blockIdx.x * 256 + threadIdx.x;
  if (t < 1024)       dst[t] = b0[t];
  else if (t < 2048)  dst[t] = b1[t - 1024];
}

// ---------------------------------------------------------------------------
__global__ __launch_bounds__(256) void softmax_inplace(unsigned short* __restrict__ P) {
  const long row = blockIdx.x;
  unsigned short* pr = P + row * 2048;
  const int tid = threadIdx.x;

  u32x4 raw = *(const u32x4*)&pr[tid * 8];
  float s[8];
  #pragma unroll
  for (int i = 0; i < 4; ++i) {
    unsigned int u = raw[i];
    s[2 * i]     = __builtin_bit_cast(float, u << 16);
    s[2 * i + 1] = __builtin_bit_cast(float, u & 0xFFFF0000u);
  }
  float m = s[0];
  #pragma unroll
  for (int i = 1; i < 8; ++i) m = fmaxf(m, s[i]);
  #pragma unroll
  for (int off = 32; off >= 1; off >>= 1) m = fmaxf(m, __shfl_xor(m, off));

  __shared__ float redm[4], reds[4];
  const int wid = tid >> 6, lane = tid & 63;
  if (lane == 0) redm[wid] = m;
  __syncthreads();
  m = fmaxf(fmaxf(redm[0], redm[1]), fmaxf(redm[2], redm[3]));

  float e[8], sum = 0.f;
  #pragma unroll
  for (int i = 0; i < 8; ++i) { e[i] = __expf(s[i] - m); sum += e[i]; }
  #pragma unroll
  for (int off = 32; off >= 1; off >>= 1) sum += __shfl_xor(sum, off);
  if (lane == 0) reds[wid] = sum;
  __syncthreads();
  sum = reds[0] + reds[1] + reds[2] + reds[3];
  const float inv = 1.0f / sum;

  u32x4 outw;
  #pragma unroll
  for (int i = 0; i < 4; ++i) outw[i] = pack2(e[2 * i] * inv, e[2 * i + 1] * inv);
  *(u32x4*)&pr[tid * 8] = outw;
}

// ---------------------------------------------------------------------------
extern "C" void kernel_launch(void* const* d_in, const int* in_sizes, int n_in,
                              void* d_out, int out_size, void* d_ws, size_t ws_size,
                              hipStream_t stream) {
  const float* query = (const float*)d_in[0];
  const float* key_  = (const float*)d_in[1];
  const float* value = (const float*)d_in[2];
  const float* Wq    = (const float*)d_in[3];
  const float* bq    = (const float*)d_in[4];
  const float* Wk    = (const float*)d_in[5];
  const float* bk    = (const float*)d_in[6];
  const float* Wv    = (const float*)d_in[7];
  const float* bv    = (const float*)d_in[8];
  const float* Wo    = (const float*)d_in[9];
  const float* bo    = (const float*)d_in[10];

  unsigned short* ws = (unsigned short*)d_ws;
  unsigned short* qf = ws;                        // [8192][1024] -> vf -> P lower
  unsigned short* kf = ws + 8388608;              // [8192][1024] -> P upper
  unsigned short* vf = ws;                        // overlays dead qf
  unsigned short* P  = ws;                        // [4][2048][2048]
  unsigned short* q  = ws + 16777216;             // [2][8.4M] q,k -> later o
  unsigned short* vT = ws + 33554432;             // [1024][8192]
  unsigned short* Wb = ws + 41943040;             // 4 x [1024][1024] bf16
  float*          bqk= (float*)(ws + 46137344);   // [2][1024] fp32
  unsigned short* o  = q;                         // overlays dead q

  const dim3 blk(256), blk8(512);

  // 0: conversions
  cvt_f32_bf16<<<dim3(512), blk, 0, stream>>>(Wq, Wb,            131072);
  cvt_f32_bf16<<<dim3(512), blk, 0, stream>>>(Wk, Wb + 1048576,  131072);
  cvt_f32_bf16<<<dim3(512), blk, 0, stream>>>(Wv, Wb + 2097152,  131072);
  cvt_f32_bf16<<<dim3(512), blk, 0, stream>>>(Wo, Wb + 3145728,  131072);
  copy_bias2<<<dim3(8), blk, 0, stream>>>(bq, bk, bqk);
  cvt_f32_bf16<<<dim3(4096), blk, 0, stream>>>(query, qf, 1048576);
  cvt_f32_bf16<<<dim3(4096), blk, 0, stream>>>(key_,  kf, 1048576);

  // 1: [q;k] projections, z=2. M=8192, N=1024, K=1024.
  gemm8<0><<<dim3(8, 32, 2), blk8, 0, stream>>>(qf, Wb, q,
      1024, 1024, 1024, 1024, 8388608L, 1048576L, 8388608L, 1024L, 1.0f, bqk, 1);

  // 2: convert value (into region freed by qf)
  cvt_f32_bf16<<<dim3(4096), blk, 0, stream>>>(value, vf, 1048576);

  // 3: vT = Wv @ vf^T + bv. M=1024, N=8192, K=1024, bias per-row.
  gemm8<0><<<dim3(64, 4, 1), blk8, 0, stream>>>(Wb + 2097152, vf, vT,
      1024, 1024, 1024, 8192, 0L, 0L, 0L, 0L, 1.0f, bv, 2);

  // 4: P = q @ k^T / 32, z=4. M=N=2048, K=1024.
  gemm8<0><<<dim3(16, 8, 4), blk8, 0, stream>>>(q, q + 8388608, P,
      1024, 1024, 1024, 2048, 2097152L, 2097152L, 4194304L, 0L, 0.03125f, nullptr, 0);

  // 5: softmax rows in place (8192 rows x 2048)
  softmax_inplace<<<dim3(8192), blk, 0, stream>>>(P);

  // 6: o = P @ vT^T, z=4. M=2048, N=1024, K=2048.
  gemm8<0><<<dim3(8, 8, 4), blk8, 0, stream>>>(P, vT, o,
      2048, 2048, 8192, 1024, 4194304L, 2048L, 2097152L, 0L, 1.0f, nullptr, 0);

  // 7: out = o @ Wo^T + bo (fp32 out). M=8192, N=1024, K=1024.
  gemm8<1><<<dim3(8, 32, 1), blk8, 0, stream>>>(o, Wb + 3145728, d_out,
      1024, 1024, 1024, 1024, 0L, 0L, 0L, 0L, 1.0f, bo, 1);
}

// Round 4
// 279.182 us; speedup vs baseline: 1.5100x; 1.0109x over previous
//
#include <hip/hip_runtime.h>
#include <stdint.h>

// ---------------------------------------------------------------------------
// Single-head attention, B=4, S=2048, D=1024, fp32 in/out. bf16 MFMA pipeline.
//
//  0. cvt fp32->bf16: query,key -> qf,kf; weights -> Wb; bias copy
//  1. [q;k] = [qf;kf] @ [Wq;Wk]^T + b    (z=2 batched)
//  2. cvt value -> vf (overlays dead qf)
//  3. vT = Wv @ vf^T + bv                 [1024,8192]
//  4. P  = q @ k^T / 32 (z=4)             [4,2048,2048] (overlays qf/kf/vf)
//  5. softmax rows of P in place
//  6. o  = P @ vT^T (z=4)                 (overlays dead q)
//  7. out= o @ Wo^T + bo -> d_out (fp32)
//
// GEMM engine (T2+T3+T4+T5):
//   BM=256 BN=128 BK=64, 512 thr = 8 waves (4M x 2N), per-wave 64x64.
//   3-buffer LDS ring (144KB): compute tile t from buf while t+1,t+2 in
//   flight -> top-of-iter s_waitcnt vmcnt(6), never 0 mid-loop.
//   2 phases per K-tile, 16 MFMA per phase (dense clusters, 5 barriers/K-tile):
//     ph0: {12x ds_read (A full + B left) | 4x global_load_lds A(t+2)}
//          -> bar -> setprio(1) 16 MFMA setprio(0) -> bar
//     ph1: {4x ds_read (B right) | 2x global_load_lds B(t+2)}
//          -> bar -> setprio(1) 16 MFMA setprio(0) -> bar
//   T2 swizzle: 16B unit ^= (row&7); DMA dest linear, global SOURCE
//   pre-swizzled (rule #21), ds_read address swizzled -> conflict-free.
// ---------------------------------------------------------------------------

typedef __bf16  bf16x8 __attribute__((ext_vector_type(8)));
typedef float   f32x4  __attribute__((ext_vector_type(4)));
typedef unsigned int u32x4 __attribute__((ext_vector_type(4)));

__device__ __forceinline__ unsigned short bf16_rne(float f) {
  unsigned int u = __builtin_bit_cast(unsigned int, f);
  u += 0x7FFFu + ((u >> 16) & 1u);
  return (unsigned short)(u >> 16);
}
__device__ __forceinline__ unsigned int pack2(float a, float b) {
  return (unsigned int)bf16_rne(a) | ((unsigned int)bf16_rne(b) << 16);
}
__device__ __forceinline__ void async16(const unsigned short* g, unsigned short* l) {
  __builtin_amdgcn_global_load_lds(
      (const __attribute__((address_space(1))) unsigned int*)g,
      (__attribute__((address_space(3))) unsigned int*)l,
      16, 0, 0);
}

#define FENCE() asm volatile("" ::: "memory")
#define BAR()   __builtin_amdgcn_s_barrier()

// ---------------------------------------------------------------------------
// C[z][m][n] = scale * sum_k A[z][m][k] * B[z][n][k]  (+ bias)
// M % 256 == 0, N % 128 == 0, K % 64 == 0, K >= 128.
// ---------------------------------------------------------------------------
template<int OUT_F32>
__global__ __launch_bounds__(512, 2) void gemm8(
    const unsigned short* __restrict__ A, const unsigned short* __restrict__ B,
    void* __restrict__ Cp,
    int K, int lda, int ldb, int ldc,
    long sAz, long sBz, long sCz, long sBiasZ,
    float scale, const float* __restrict__ bias, int bias_mode)
{
  __shared__ unsigned short lds[3 * 24576];   // per buf: A 16384 + B 8192 ushorts

  const int tid  = threadIdx.x;
  const int lane = tid & 63;
  const int wid  = tid >> 6;                  // 0..7
  const int bm   = blockIdx.y * 256;
  const int bn   = blockIdx.x * 128;
  const long z   = blockIdx.z;

  const unsigned short* Az = A + z * sAz;
  const unsigned short* Bz = B + z * sBz;

  const int wr  = (wid >> 1) * 64;            // wave row in tile (0,64,128,192)
  const int wc  = (wid & 1)  * 64;            // wave col in tile (0,64)
  const int al  = lane & 15;
  const int ah  = lane >> 4;
  const int al7 = lane & 7;

  // staging: per K-tile, per wave: 4 A-loads (8 rows each) + 2 B-loads.
  // global source col pre-swizzled so linear DMA dest yields swizzled LDS.
  const int swz = ((lane & 7) ^ ((lane >> 3) & 7)) << 3;   // ushort offset
  const unsigned short* Apt = Az + (long)(bm + wid * 32 + (lane >> 3)) * lda + swz;
  const unsigned short* Bpt = Bz + (long)(bn + wid * 16 + (lane >> 3)) * ldb + swz;
  const long a8 = (long)lda * 8, b8 = (long)ldb * 8;

  f32x4 acc[4][4] = {};
  const int nkt = K >> 6;

#define STAGE_A(kt, stg) { const unsigned short* a_ = Apt + ((long)(kt) << 6); \
    async16(a_,          (stg) + wid * 2048);        \
    async16(a_ + a8,     (stg) + wid * 2048 + 512);  \
    async16(a_ + 2 * a8, (stg) + wid * 2048 + 1024); \
    async16(a_ + 3 * a8, (stg) + wid * 2048 + 1536); }
#define STAGE_B(kt, stg) { const unsigned short* b_ = Bpt + ((long)(kt) << 6); \
    async16(b_,      (stg) + 16384 + wid * 1024); \
    async16(b_ + b8, (stg) + 16384 + wid * 1024 + 512); }

  // swizzled fragment reads: 16B unit index (kk*4+ah) ^ (row&7), row&7 == al7
#define LDA_(m) { const int r_ = (wr + (m) * 16 + al) * 64; \
    af##m##0 = *(const bf16x8*)&as[r_ + ((ah ^ al7) << 3)]; \
    af##m##1 = *(const bf16x8*)&as[r_ + (((4 | ah) ^ al7) << 3)]; }
#define LDB_(n) { const int r_ = (wc + (n) * 16 + al) * 64; \
    bf##n##0 = *(const bf16x8*)&bs[r_ + ((ah ^ al7) << 3)]; \
    bf##n##1 = *(const bf16x8*)&bs[r_ + (((4 | ah) ^ al7) << 3)]; }
#define MM(m, n) { \
    acc[m][n] = __builtin_amdgcn_mfma_f32_16x16x32_bf16(af##m##0, bf##n##0, acc[m][n], 0, 0, 0); \
    acc[m][n] = __builtin_amdgcn_mfma_f32_16x16x32_bf16(af##m##1, bf##n##1, acc[m][n], 0, 0, 0); }

  // prologue: tiles 0,1 -> bufs 0,1 (12 loads in flight per wave)
  STAGE_A(0, lds); STAGE_B(0, lds);
  STAGE_A(1, lds + 24576); STAGE_B(1, lds + 24576);

  int cur = 0;
  for (int t = 0; t < nkt; ++t) {
    const int stb  = (cur >= 1) ? cur - 1 : cur + 2;   // (t+2)%3
    const bool more = (t + 2) < nkt;

    // tile t resident: wait for all but the newest <=6 loads (tile t+1)
    if (t + 1 < nkt) asm volatile("s_waitcnt vmcnt(6)" ::: "memory");
    else             asm volatile("s_waitcnt vmcnt(0)" ::: "memory");
    BAR(); FENCE();

    const unsigned short* as  = lds + cur * 24576;
    const unsigned short* bs  = as + 16384;
    unsigned short*       stg = lds + stb * 24576;

    bf16x8 af00, af01, af10, af11, af20, af21, af30, af31;
    bf16x8 bf00, bf01, bf10, bf11, bf20, bf21, bf30, bf31;

    // phase 0: A full + B left; stage A(t+2)
    LDA_(0); LDA_(1); LDA_(2); LDA_(3);
    LDB_(0); LDB_(1);
    if (more) STAGE_A(t + 2, stg);
    FENCE(); BAR();
    __builtin_amdgcn_s_setprio(1);
    MM(0,0); MM(1,0); MM(2,0); MM(3,0);
    MM(0,1); MM(1,1); MM(2,1); MM(3,1);
    __builtin_amdgcn_s_setprio(0);
    BAR(); FENCE();

    // phase 1: B right; stage B(t+2)
    LDB_(2); LDB_(3);
    if (more) STAGE_B(t + 2, stg);
    FENCE(); BAR();
    __builtin_amdgcn_s_setprio(1);
    MM(0,2); MM(1,2); MM(2,2); MM(3,2);
    MM(0,3); MM(1,3); MM(2,3); MM(3,3);
    __builtin_amdgcn_s_setprio(0);
    BAR(); FENCE();

    cur = (cur == 2) ? 0 : cur + 1;
  }

  // Epilogue. C/D layout (m89/m91): col = lane&15, row = (lane>>4)*4 + j
  #pragma unroll
  for (int m = 0; m < 4; ++m) {
    #pragma unroll
    for (int n = 0; n < 4; ++n) {
      #pragma unroll
      for (int j = 0; j < 4; ++j) {
        const int grow = bm + wr + m * 16 + ah * 4 + j;
        const int gcol = bn + wc + n * 16 + al;
        float v = acc[m][n][j] * scale;
        if (bias_mode == 1)      v += bias[z * sBiasZ + gcol];
        else if (bias_mode == 2) v += bias[z * sBiasZ + grow];
        const long idx = z * sCz + (long)grow * ldc + gcol;
        if (OUT_F32) ((float*)Cp)[idx] = v;
        else         ((unsigned short*)Cp)[idx] = bf16_rne(v);
      }
    }
  }
}

// ---------------------------------------------------------------------------
__global__ __launch_bounds__(256) void cvt_f32_bf16(
    const float* __restrict__ in, unsigned short* __restrict__ out, int n8)
{
  const int i = blockIdx.x * 256 + threadIdx.x;
  if (i >= n8) return;
  f32x4 a = *(const f32x4*)(in + (long)i * 8);
  f32x4 b = *(const f32x4*)(in + (long)i * 8 + 4);
  u32x4 w;
  w[0] = pack2(a[0], a[1]); w[1] = pack2(a[2], a[3]);
  w[2] = pack2(b[0], b[1]); w[3] = pack2(b[2], b[3]);
  *(u32x4*)(out + (long)i * 8) = w;
}

__global__ __launch_bounds__(256) void copy_bias2(
    const float* __restrict__ b0, const float* __restrict__ b1, float* __restrict__ dst)
{
  const int t = blockIdx.x * 256 + threadIdx.x;
  if (t < 1024)       dst[t] = b0[t];
  else if (t < 2048)  dst[t] = b1[t - 1024];
}

// ---------------------------------------------------------------------------
__global__ __launch_bounds__(256) void softmax_inplace(unsigned short* __restrict__ P) {
  const long row = blockIdx.x;
  unsigned short* pr = P + row * 2048;
  const int tid = threadIdx.x;

  u32x4 raw = *(const u32x4*)&pr[tid * 8];
  float s[8];
  #pragma unroll
  for (int i = 0; i < 4; ++i) {
    unsigned int u = raw[i];
    s[2 * i]     = __builtin_bit_cast(float, u << 16);
    s[2 * i + 1] = __builtin_bit_cast(float, u & 0xFFFF0000u);
  }
  float m = s[0];
  #pragma unroll
  for (int i = 1; i < 8; ++i) m = fmaxf(m, s[i]);
  #pragma unroll
  for (int off = 32; off >= 1; off >>= 1) m = fmaxf(m, __shfl_xor(m, off));

  __shared__ float redm[4], reds[4];
  const int wid = tid >> 6, lane = tid & 63;
  if (lane == 0) redm[wid] = m;
  __syncthreads();
  m = fmaxf(fmaxf(redm[0], redm[1]), fmaxf(redm[2], redm[3]));

  float e[8], sum = 0.f;
  #pragma unroll
  for (int i = 0; i < 8; ++i) { e[i] = __expf(s[i] - m); sum += e[i]; }
  #pragma unroll
  for (int off = 32; off >= 1; off >>= 1) sum += __shfl_xor(sum, off);
  if (lane == 0) reds[wid] = sum;
  __syncthreads();
  sum = reds[0] + reds[1] + reds[2] + reds[3];
  const float inv = 1.0f / sum;

  u32x4 outw;
  #pragma unroll
  for (int i = 0; i < 4; ++i) outw[i] = pack2(e[2 * i] * inv, e[2 * i + 1] * inv);
  *(u32x4*)&pr[tid * 8] = outw;
}

// ---------------------------------------------------------------------------
extern "C" void kernel_launch(void* const* d_in, const int* in_sizes, int n_in,
                              void* d_out, int out_size, void* d_ws, size_t ws_size,
                              hipStream_t stream) {
  const float* query = (const float*)d_in[0];
  const float* key_  = (const float*)d_in[1];
  const float* value = (const float*)d_in[2];
  const float* Wq    = (const float*)d_in[3];
  const float* bq    = (const float*)d_in[4];
  const float* Wk    = (const float*)d_in[5];
  const float* bk    = (const float*)d_in[6];
  const float* Wv    = (const float*)d_in[7];
  const float* bv    = (const float*)d_in[8];
  const float* Wo    = (const float*)d_in[9];
  const float* bo    = (const float*)d_in[10];

  unsigned short* ws = (unsigned short*)d_ws;
  unsigned short* qf = ws;                        // [8192][1024] -> vf -> P lower
  unsigned short* kf = ws + 8388608;              // [8192][1024] -> P upper
  unsigned short* vf = ws;                        // overlays dead qf
  unsigned short* P  = ws;                        // [4][2048][2048]
  unsigned short* q  = ws + 16777216;             // [2][8.4M] q,k -> later o
  unsigned short* vT = ws + 33554432;             // [1024][8192]
  unsigned short* Wb = ws + 41943040;             // 4 x [1024][1024] bf16
  float*          bqk= (float*)(ws + 46137344);   // [2][1024] fp32
  unsigned short* o  = q;                         // overlays dead q

  const dim3 blk(256), blk8(512);

  // 0: conversions
  cvt_f32_bf16<<<dim3(512), blk, 0, stream>>>(Wq, Wb,            131072);
  cvt_f32_bf16<<<dim3(512), blk, 0, stream>>>(Wk, Wb + 1048576,  131072);
  cvt_f32_bf16<<<dim3(512), blk, 0, stream>>>(Wv, Wb + 2097152,  131072);
  cvt_f32_bf16<<<dim3(512), blk, 0, stream>>>(Wo, Wb + 3145728,  131072);
  copy_bias2<<<dim3(8), blk, 0, stream>>>(bq, bk, bqk);
  cvt_f32_bf16<<<dim3(4096), blk, 0, stream>>>(query, qf, 1048576);
  cvt_f32_bf16<<<dim3(4096), blk, 0, stream>>>(key_,  kf, 1048576);

  // 1: [q;k] projections, z=2. M=8192, N=1024, K=1024.
  gemm8<0><<<dim3(8, 32, 2), blk8, 0, stream>>>(qf, Wb, q,
      1024, 1024, 1024, 1024, 8388608L, 1048576L, 8388608L, 1024L, 1.0f, bqk, 1);

  // 2: convert value (into region freed by qf)
  cvt_f32_bf16<<<dim3(4096), blk, 0, stream>>>(value, vf, 1048576);

  // 3: vT = Wv @ vf^T + bv. M=1024, N=8192, K=1024, bias per-row.
  gemm8<0><<<dim3(64, 4, 1), blk8, 0, stream>>>(Wb + 2097152, vf, vT,
      1024, 1024, 1024, 8192, 0L, 0L, 0L, 0L, 1.0f, bv, 2);

  // 4: P = q @ k^T / 32, z=4. M=N=2048, K=1024.
  gemm8<0><<<dim3(16, 8, 4), blk8, 0, stream>>>(q, q + 8388608, P,
      1024, 1024, 1024, 2048, 2097152L, 2097152L, 4194304L, 0L, 0.03125f, nullptr, 0);

  // 5: softmax rows in place (8192 rows x 2048)
  softmax_inplace<<<dim3(8192), blk, 0, stream>>>(P);

  // 6: o = P @ vT^T, z=4. M=2048, N=1024, K=2048.
  gemm8<0><<<dim3(8, 8, 4), blk8, 0, stream>>>(P, vT, o,
      2048, 2048, 8192, 1024, 4194304L, 2048L, 2097152L, 0L, 1.0f, nullptr, 0);

  // 7: out = o @ Wo^T + bo (fp32 out). M=8192, N=1024, K=1024.
  gemm8<1><<<dim3(8, 32, 1), blk8, 0, stream>>>(o, Wb + 3145728, d_out,
      1024, 1024, 1024, 1024, 0L, 0L, 0L, 0L, 1.0f, bo, 1);
}

// Round 5
// 265.766 us; speedup vs baseline: 1.5862x; 1.0505x over previous
//
#include <hip/hip_runtime.h>
#include <stdint.h>

// ---------------------------------------------------------------------------
// Single-head attention, B=4, S=2048, D=1024, fp32 in/out. bf16 MFMA pipeline.
//
//  0. cvt fp32->bf16: query,key -> qf,kf; weights -> Wb; bias copy
//  1. [q;k] = [qf;kf] @ [Wq;Wk]^T + b    (z=2 batched)
//  2. cvt value -> vf (overlays dead qf)
//  3. vT = Wv @ vf^T + bv                 [1024,8192]
//  4. P  = q @ k^T / 32 (z=4)             [4,2048,2048] (overlays qf/kf/vf)
//  5. softmax rows of P in place
//  6. o  = P @ vT^T (z=4)                 (overlays dead q)
//  7. out= o @ Wo^T + bo -> d_out (fp32)
//
// GEMM engine (T1+T2+T3+T4+T5):
//   BM=256 BN=128 BK=64, 512 thr = 8 waves (4M x 2N), per-wave 64x64.
//   3-buffer LDS ring (144KB), top-of-iter s_waitcnt vmcnt(6), never 0
//   mid-loop. 2 phases per K-tile, 16 MFMA per phase.
//   T1: XCD-chunked bijective blockIdx swizzle (m204), work linearized
//   x-fastest so A-panel-sharing blocks co-reside on one XCD's L2
//   (fetch was 133MB on qkproj = A-panel x8 refetch; this kills it).
//   T2 swizzle: 16B unit ^= (row&7); DMA dest linear, global SOURCE
//   pre-swizzled (rule #21), ds_read address swizzled -> conflict-free.
// ---------------------------------------------------------------------------

typedef __bf16  bf16x8 __attribute__((ext_vector_type(8)));
typedef float   f32x4  __attribute__((ext_vector_type(4)));
typedef unsigned int u32x4 __attribute__((ext_vector_type(4)));

__device__ __forceinline__ unsigned short bf16_rne(float f) {
  unsigned int u = __builtin_bit_cast(unsigned int, f);
  u += 0x7FFFu + ((u >> 16) & 1u);
  return (unsigned short)(u >> 16);
}
__device__ __forceinline__ unsigned int pack2(float a, float b) {
  return (unsigned int)bf16_rne(a) | ((unsigned int)bf16_rne(b) << 16);
}
__device__ __forceinline__ void async16(const unsigned short* g, unsigned short* l) {
  __builtin_amdgcn_global_load_lds(
      (const __attribute__((address_space(1))) unsigned int*)g,
      (__attribute__((address_space(3))) unsigned int*)l,
      16, 0, 0);
}

#define FENCE() asm volatile("" ::: "memory")
#define BAR()   __builtin_amdgcn_s_barrier()

// ---------------------------------------------------------------------------
// C[z][m][n] = scale * sum_k A[z][m][k] * B[z][n][k]  (+ bias)
// M % 256 == 0, N % 128 == 0, K % 64 == 0, K >= 192. nwg arbitrary (bijective).
// ---------------------------------------------------------------------------
template<int OUT_F32>
__global__ __launch_bounds__(512, 2) void gemm8(
    const unsigned short* __restrict__ A, const unsigned short* __restrict__ B,
    void* __restrict__ Cp,
    int K, int lda, int ldb, int ldc,
    long sAz, long sBz, long sCz, long sBiasZ,
    float scale, const float* __restrict__ bias, int bias_mode)
{
  __shared__ unsigned short lds[3 * 24576];   // per buf: A 16384 + B 8192 ushorts

  // ---- T1: XCD-chunked bijective remap (m204). Work index w linearized
  // x-fastest; hardware round-robins orig%8 across XCDs, so XCD k gets the
  // contiguous work chunk [start_k, start_k+cnt_k) -> A-panel sharers co-L2.
  const int nx   = gridDim.x, ny = gridDim.y;
  const int nwg  = nx * ny * gridDim.z;
  const int orig = (blockIdx.z * ny + blockIdx.y) * nx + blockIdx.x;
  const int xcd  = orig & 7, loc = orig >> 3;
  const int qq   = nwg >> 3, rr = nwg & 7;
  const int w    = (xcd < rr ? xcd * (qq + 1) : rr * (qq + 1) + (xcd - rr) * qq) + loc;
  const int bxi  = w % nx;
  const int byi  = (w / nx) % ny;
  const int bzi  = w / (nx * ny);

  const int tid  = threadIdx.x;
  const int lane = tid & 63;
  const int wid  = tid >> 6;                  // 0..7
  const int bm   = byi * 256;
  const int bn   = bxi * 128;
  const long z   = bzi;

  const unsigned short* Az = A + z * sAz;
  const unsigned short* Bz = B + z * sBz;

  const int wr  = (wid >> 1) * 64;            // wave row in tile (0,64,128,192)
  const int wc  = (wid & 1)  * 64;            // wave col in tile (0,64)
  const int al  = lane & 15;
  const int ah  = lane >> 4;
  const int al7 = lane & 7;

  // staging: per K-tile, per wave: 4 A-loads (8 rows each) + 2 B-loads.
  // global source col pre-swizzled so linear DMA dest yields swizzled LDS.
  const int swz = ((lane & 7) ^ ((lane >> 3) & 7)) << 3;   // ushort offset
  const unsigned short* Apt = Az + (long)(bm + wid * 32 + (lane >> 3)) * lda + swz;
  const unsigned short* Bpt = Bz + (long)(bn + wid * 16 + (lane >> 3)) * ldb + swz;
  const long a8 = (long)lda * 8, b8 = (long)ldb * 8;

  f32x4 acc[4][4] = {};
  const int nkt = K >> 6;

#define STAGE_A(kt, stg) { const unsigned short* a_ = Apt + ((long)(kt) << 6); \
    async16(a_,          (stg) + wid * 2048);        \
    async16(a_ + a8,     (stg) + wid * 2048 + 512);  \
    async16(a_ + 2 * a8, (stg) + wid * 2048 + 1024); \
    async16(a_ + 3 * a8, (stg) + wid * 2048 + 1536); }
#define STAGE_B(kt, stg) { const unsigned short* b_ = Bpt + ((long)(kt) << 6); \
    async16(b_,      (stg) + 16384 + wid * 1024); \
    async16(b_ + b8, (stg) + 16384 + wid * 1024 + 512); }

  // swizzled fragment reads: 16B unit index (kk*4+ah) ^ (row&7), row&7 == al7
#define LDA_(m) { const int r_ = (wr + (m) * 16 + al) * 64; \
    af##m##0 = *(const bf16x8*)&as[r_ + ((ah ^ al7) << 3)]; \
    af##m##1 = *(const bf16x8*)&as[r_ + (((4 | ah) ^ al7) << 3)]; }
#define LDB_(n) { const int r_ = (wc + (n) * 16 + al) * 64; \
    bf##n##0 = *(const bf16x8*)&bs[r_ + ((ah ^ al7) << 3)]; \
    bf##n##1 = *(const bf16x8*)&bs[r_ + (((4 | ah) ^ al7) << 3)]; }
#define MM(m, n) { \
    acc[m][n] = __builtin_amdgcn_mfma_f32_16x16x32_bf16(af##m##0, bf##n##0, acc[m][n], 0, 0, 0); \
    acc[m][n] = __builtin_amdgcn_mfma_f32_16x16x32_bf16(af##m##1, bf##n##1, acc[m][n], 0, 0, 0); }

  // prologue: tiles 0,1 -> bufs 0,1 (12 loads in flight per wave)
  STAGE_A(0, lds); STAGE_B(0, lds);
  STAGE_A(1, lds + 24576); STAGE_B(1, lds + 24576);

  int cur = 0;
  for (int t = 0; t < nkt; ++t) {
    const int stb  = (cur >= 1) ? cur - 1 : cur + 2;   // (t+2)%3
    const bool more = (t + 2) < nkt;

    // tile t resident: wait for all but the newest <=6 loads (tile t+1)
    if (t + 1 < nkt) asm volatile("s_waitcnt vmcnt(6)" ::: "memory");
    else             asm volatile("s_waitcnt vmcnt(0)" ::: "memory");
    BAR(); FENCE();

    const unsigned short* as  = lds + cur * 24576;
    const unsigned short* bs  = as + 16384;
    unsigned short*       stg = lds + stb * 24576;

    bf16x8 af00, af01, af10, af11, af20, af21, af30, af31;
    bf16x8 bf00, bf01, bf10, bf11, bf20, bf21, bf30, bf31;

    // phase 0: A full + B left; stage A(t+2)
    LDA_(0); LDA_(1); LDA_(2); LDA_(3);
    LDB_(0); LDB_(1);
    if (more) STAGE_A(t + 2, stg);
    FENCE(); BAR();
    __builtin_amdgcn_s_setprio(1);
    MM(0,0); MM(1,0); MM(2,0); MM(3,0);
    MM(0,1); MM(1,1); MM(2,1); MM(3,1);
    __builtin_amdgcn_s_setprio(0);
    BAR(); FENCE();

    // phase 1: B right; stage B(t+2)
    LDB_(2); LDB_(3);
    if (more) STAGE_B(t + 2, stg);
    FENCE(); BAR();
    __builtin_amdgcn_s_setprio(1);
    MM(0,2); MM(1,2); MM(2,2); MM(3,2);
    MM(0,3); MM(1,3); MM(2,3); MM(3,3);
    __builtin_amdgcn_s_setprio(0);
    BAR(); FENCE();

    cur = (cur == 2) ? 0 : cur + 1;
  }

  // Epilogue. C/D layout (m89/m91): col = lane&15, row = (lane>>4)*4 + j
  #pragma unroll
  for (int m = 0; m < 4; ++m) {
    #pragma unroll
    for (int n = 0; n < 4; ++n) {
      #pragma unroll
      for (int j = 0; j < 4; ++j) {
        const int grow = bm + wr + m * 16 + ah * 4 + j;
        const int gcol = bn + wc + n * 16 + al;
        float v = acc[m][n][j] * scale;
        if (bias_mode == 1)      v += bias[z * sBiasZ + gcol];
        else if (bias_mode == 2) v += bias[z * sBiasZ + grow];
        const long idx = z * sCz + (long)grow * ldc + gcol;
        if (OUT_F32) ((float*)Cp)[idx] = v;
        else         ((unsigned short*)Cp)[idx] = bf16_rne(v);
      }
    }
  }
}

// ---------------------------------------------------------------------------
__global__ __launch_bounds__(256) void cvt_f32_bf16(
    const float* __restrict__ in, unsigned short* __restrict__ out, int n8)
{
  const int i = blockIdx.x * 256 + threadIdx.x;
  if (i >= n8) return;
  f32x4 a = *(const f32x4*)(in + (long)i * 8);
  f32x4 b = *(const f32x4*)(in + (long)i * 8 + 4);
  u32x4 w;
  w[0] = pack2(a[0], a[1]); w[1] = pack2(a[2], a[3]);
  w[2] = pack2(b[0], b[1]); w[3] = pack2(b[2], b[3]);
  *(u32x4*)(out + (long)i * 8) = w;
}

__global__ __launch_bounds__(256) void copy_bias2(
    const float* __restrict__ b0, const float* __restrict__ b1, float* __restrict__ dst)
{
  const int t = blockIdx.x * 256 + threadIdx.x;
  if (t < 1024)       dst[t] = b0[t];
  else if (t < 2048)  dst[t] = b1[t - 1024];
}

// ---------------------------------------------------------------------------
__global__ __launch_bounds__(256) void softmax_inplace(unsigned short* __restrict__ P) {
  const long row = blockIdx.x;
  unsigned short* pr = P + row * 2048;
  const int tid = threadIdx.x;

  u32x4 raw = *(const u32x4*)&pr[tid * 8];
  float s[8];
  #pragma unroll
  for (int i = 0; i < 4; ++i) {
    unsigned int u = raw[i];
    s[2 * i]     = __builtin_bit_cast(float, u << 16);
    s[2 * i + 1] = __builtin_bit_cast(float, u & 0xFFFF0000u);
  }
  float m = s[0];
  #pragma unroll
  for (int i = 1; i < 8; ++i) m = fmaxf(m, s[i]);
  #pragma unroll
  for (int off = 32; off >= 1; off >>= 1) m = fmaxf(m, __shfl_xor(m, off));

  __shared__ float redm[4], reds[4];
  const int wid = tid >> 6, lane = tid & 63;
  if (lane == 0) redm[wid] = m;
  __syncthreads();
  m = fmaxf(fmaxf(redm[0], redm[1]), fmaxf(redm[2], redm[3]));

  float e[8], sum = 0.f;
  #pragma unroll
  for (int i = 0; i < 8; ++i) { e[i] = __expf(s[i] - m); sum += e[i]; }
  #pragma unroll
  for (int off = 32; off >= 1; off >>= 1) sum += __shfl_xor(sum, off);
  if (lane == 0) reds[wid] = sum;
  __syncthreads();
  sum = reds[0] + reds[1] + reds[2] + reds[3];
  const float inv = 1.0f / sum;

  u32x4 outw;
  #pragma unroll
  for (int i = 0; i < 4; ++i) outw[i] = pack2(e[2 * i] * inv, e[2 * i + 1] * inv);
  *(u32x4*)&pr[tid * 8] = outw;
}

// ---------------------------------------------------------------------------
extern "C" void kernel_launch(void* const* d_in, const int* in_sizes, int n_in,
                              void* d_out, int out_size, void* d_ws, size_t ws_size,
                              hipStream_t stream) {
  const float* query = (const float*)d_in[0];
  const float* key_  = (const float*)d_in[1];
  const float* value = (const float*)d_in[2];
  const float* Wq    = (const float*)d_in[3];
  const float* bq    = (const float*)d_in[4];
  const float* Wk    = (const float*)d_in[5];
  const float* bk    = (const float*)d_in[6];
  const float* Wv    = (const float*)d_in[7];
  const float* bv    = (const float*)d_in[8];
  const float* Wo    = (const float*)d_in[9];
  const float* bo    = (const float*)d_in[10];

  unsigned short* ws = (unsigned short*)d_ws;
  unsigned short* qf = ws;                        // [8192][1024] -> vf -> P lower
  unsigned short* kf = ws + 8388608;              // [8192][1024] -> P upper
  unsigned short* vf = ws;                        // overlays dead qf
  unsigned short* P  = ws;                        // [4][2048][2048]
  unsigned short* q  = ws + 16777216;             // [2][8.4M] q,k -> later o
  unsigned short* vT = ws + 33554432;             // [1024][8192]
  unsigned short* Wb = ws + 41943040;             // 4 x [1024][1024] bf16
  float*          bqk= (float*)(ws + 46137344);   // [2][1024] fp32
  unsigned short* o  = q;                         // overlays dead q

  const dim3 blk(256), blk8(512);

  // 0: conversions
  cvt_f32_bf16<<<dim3(512), blk, 0, stream>>>(Wq, Wb,            131072);
  cvt_f32_bf16<<<dim3(512), blk, 0, stream>>>(Wk, Wb + 1048576,  131072);
  cvt_f32_bf16<<<dim3(512), blk, 0, stream>>>(Wv, Wb + 2097152,  131072);
  cvt_f32_bf16<<<dim3(512), blk, 0, stream>>>(Wo, Wb + 3145728,  131072);
  copy_bias2<<<dim3(8), blk, 0, stream>>>(bq, bk, bqk);
  cvt_f32_bf16<<<dim3(4096), blk, 0, stream>>>(query, qf, 1048576);
  cvt_f32_bf16<<<dim3(4096), blk, 0, stream>>>(key_,  kf, 1048576);

  // 1: [q;k] projections, z=2. M=8192, N=1024, K=1024.
  gemm8<0><<<dim3(8, 32, 2), blk8, 0, stream>>>(qf, Wb, q,
      1024, 1024, 1024, 1024, 8388608L, 1048576L, 8388608L, 1024L, 1.0f, bqk, 1);

  // 2: convert value (into region freed by qf)
  cvt_f32_bf16<<<dim3(4096), blk, 0, stream>>>(value, vf, 1048576);

  // 3: vT = Wv @ vf^T + bv. M=1024, N=8192, K=1024, bias per-row.
  gemm8<0><<<dim3(64, 4, 1), blk8, 0, stream>>>(Wb + 2097152, vf, vT,
      1024, 1024, 1024, 8192, 0L, 0L, 0L, 0L, 1.0f, bv, 2);

  // 4: P = q @ k^T / 32, z=4. M=N=2048, K=1024.
  gemm8<0><<<dim3(16, 8, 4), blk8, 0, stream>>>(q, q + 8388608, P,
      1024, 1024, 1024, 2048, 2097152L, 2097152L, 4194304L, 0L, 0.03125f, nullptr, 0);

  // 5: softmax rows in place (8192 rows x 2048)
  softmax_inplace<<<dim3(8192), blk, 0, stream>>>(P);

  // 6: o = P @ vT^T, z=4. M=2048, N=1024, K=2048.
  gemm8<0><<<dim3(8, 8, 4), blk8, 0, stream>>>(P, vT, o,
      2048, 2048, 8192, 1024, 4194304L, 2048L, 2097152L, 0L, 1.0f, nullptr, 0);

  // 7: out = o @ Wo^T + bo (fp32 out). M=8192, N=1024, K=1024.
  gemm8<1><<<dim3(8, 32, 1), blk8, 0, stream>>>(o, Wb + 3145728, d_out,
      1024, 1024, 1024, 1024, 0L, 0L, 0L, 0L, 1.0f, bo, 1);
}